// Round 1
// baseline (442.820 us; speedup 1.0000x reference)
//
#include <hip/hip_runtime.h>
#include <hip/hip_bf16.h>
#include <stdint.h>

#define DMODEL 1024
#define SEQ    2048
#define BATCH  4
#define NH     16
#define DKH    64
#define MROWS  (BATCH*SEQ)   // 8192

typedef unsigned short u16;
typedef __bf16 bf8 __attribute__((ext_vector_type(8)));   // MFMA A/B fragment (8 bf16)
typedef float  f4  __attribute__((ext_vector_type(4)));   // MFMA C/D fragment
typedef float  fv4 __attribute__((ext_vector_type(4)));
typedef unsigned int u32x4 __attribute__((ext_vector_type(4)));

// fp32 -> bf16 RNE (no NaN in this workload)
__device__ __forceinline__ u16 f2b(float f) {
  union { float f; unsigned u; } a; a.f = f;
  unsigned r = a.u + 0x7fffu + ((a.u >> 16) & 1u);
  return (u16)(r >> 16);
}

#define GLL16(gp, lp) __builtin_amdgcn_global_load_lds( \
    (const __attribute__((address_space(1))) void*)(gp), \
    (__attribute__((address_space(3))) void*)(lp), 16, 0, 0)

#define MFMA16(a, b, c) __builtin_amdgcn_mfma_f32_16x16x32_bf16((a), (b), (c), 0, 0, 0)

// ---------------------------------------------------------------- convert
__global__ __launch_bounds__(256) void cvt_kernel(const float* __restrict__ s,
                                                  u16* __restrict__ d, int n8) {
  int idx = blockIdx.x * 256 + threadIdx.x;
  int stride = gridDim.x * 256;
  for (int i = idx; i < n8; i += stride) {
    fv4 a = *(const fv4*)(s + (size_t)i * 8);
    fv4 b = *(const fv4*)(s + (size_t)i * 8 + 4);
    u32x4 o;
    o[0] = (unsigned)f2b(a[0]) | ((unsigned)f2b(a[1]) << 16);
    o[1] = (unsigned)f2b(a[2]) | ((unsigned)f2b(a[3]) << 16);
    o[2] = (unsigned)f2b(b[0]) | ((unsigned)f2b(b[1]) << 16);
    o[3] = (unsigned)f2b(b[2]) | ((unsigned)f2b(b[3]) << 16);
    *(u32x4*)(d + (size_t)i * 8) = o;
  }
}

// ---------------------------------------------------------------- GEMM-BT
// C[m][n] = sum_k A[m][k]*B[n][k] + bias[n].  M=8192 (by), N=K=1024.
// 128x128 tile, BK=32, 4 waves (2x2), 4x4 16x16x32 frags per wave.
// MODE 0: bf16 row-major out; MODE 1: bf16 transposed-V out [B*H*DK][SEQ];
// MODE 2: fp32 row-major out.
template<int MODE>
__device__ __forceinline__ void gemm_core(const u16* __restrict__ A,
                                          const u16* __restrict__ Bw,
                                          const float* __restrict__ bias,
                                          void* __restrict__ Cout,
                                          int bx, int by) {
  __shared__ u16 As[128 * 32];
  __shared__ u16 Bs[128 * 32];
  const int tid = threadIdx.x;
  const int w = tid >> 6, l = tid & 63, g = l >> 4, ln = l & 15;
  const int m0 = by * 128, n0 = bx * 128;
  const int wm = (w >> 1) * 64, wn = (w & 1) * 64;
  const f4 zero = {0.f, 0.f, 0.f, 0.f};
  f4 acc[4][4];
#pragma unroll
  for (int i = 0; i < 4; ++i)
#pragma unroll
    for (int j = 0; j < 4; ++j) acc[i][j] = zero;

  for (int ks = 0; ks < DMODEL / 32; ++ks) {
    __syncthreads();   // previous tile's ds_reads done before overwrite
#pragma unroll
    for (int p = 0; p < 2; ++p) {
      // chunk j in [0,512): row = j>>2 (0..127), stored col16 = j&3.
      // LDS linear dest; source col pre-swizzled: src = cs ^ ((row>>1)&3)
      int j = p * 256 + tid;
      int row = j >> 2, cs = j & 3;
      int sc = cs ^ ((row >> 1) & 3);
      const u16* ga = A + (size_t)(m0 + row) * DMODEL + ks * 32 + sc * 8;
      GLL16(ga, &As[(p * 256 + w * 64) * 8]);
      const u16* gb = Bw + (size_t)(n0 + row) * DMODEL + ks * 32 + sc * 8;
      GLL16(gb, &Bs[(p * 256 + w * 64) * 8]);
    }
    __syncthreads();   // staging complete (compiler drains vmcnt before barrier)

    bf8 af[4], bfr[4];
#pragma unroll
    for (int mt = 0; mt < 4; ++mt) {
      int row = wm + mt * 16 + ln;
      af[mt] = *(const bf8*)((const char*)As + row * 64 + ((g ^ ((row >> 1) & 3)) << 4));
    }
#pragma unroll
    for (int nt = 0; nt < 4; ++nt) {
      int row = wn + nt * 16 + ln;
      bfr[nt] = *(const bf8*)((const char*)Bs + row * 64 + ((g ^ ((row >> 1) & 3)) << 4));
    }
#pragma unroll
    for (int mt = 0; mt < 4; ++mt)
#pragma unroll
      for (int nt = 0; nt < 4; ++nt)
        acc[mt][nt] = MFMA16(af[mt], bfr[nt], acc[mt][nt]);
  }

  // epilogue: D row = g*4+r, col = ln (m89-verified mapping)
#pragma unroll
  for (int nt = 0; nt < 4; ++nt) {
    int col = n0 + wn + nt * 16 + ln;
    float bv = bias[col];
#pragma unroll
    for (int mt = 0; mt < 4; ++mt) {
      int mrow = m0 + wm + mt * 16 + g * 4;
#pragma unroll
      for (int r = 0; r < 4; ++r) {
        float v = acc[mt][nt][r] + bv;
        int m = mrow + r;
        if (MODE == 2) {
          ((float*)Cout)[(size_t)m * DMODEL + col] = v;
        } else if (MODE == 0) {
          ((u16*)Cout)[(size_t)m * DMODEL + col] = f2b(v);
        } else {  // transposed V: Vt[(b*1024 + n)][s], n = h*64+d
          int b = m >> 11, s2 = m & 2047;
          ((u16*)Cout)[((size_t)(b * 1024 + col)) * SEQ + s2] = f2b(v);
        }
      }
    }
  }
}

__global__ __launch_bounds__(256) void gemm_qkv(
    const u16* __restrict__ Qb, const u16* __restrict__ Kb, const u16* __restrict__ Vb,
    const u16* __restrict__ Wq, const u16* __restrict__ Wk, const u16* __restrict__ Wv,
    const float* __restrict__ bq, const float* __restrict__ bk, const float* __restrict__ bv,
    u16* __restrict__ Qp, u16* __restrict__ Kp, u16* __restrict__ Vpt) {
  if (blockIdx.z == 0)      gemm_core<0>(Qb, Wq, bq, Qp,  blockIdx.x, blockIdx.y);
  else if (blockIdx.z == 1) gemm_core<0>(Kb, Wk, bk, Kp,  blockIdx.x, blockIdx.y);
  else                      gemm_core<1>(Vb, Wv, bv, Vpt, blockIdx.x, blockIdx.y);
}

__global__ __launch_bounds__(256) void gemm_out(
    const u16* __restrict__ Ctx, const u16* __restrict__ Wo,
    const float* __restrict__ bo, float* __restrict__ Out) {
  gemm_core<2>(Ctx, Wo, bo, Out, blockIdx.x, blockIdx.y);
}

// ---------------------------------------------------------------- attention
// Flash attention. Block: 256 thr (4 waves), QBLK=64 (16 rows/wave), KVBLK=64.
// Swapped QK^T: mfma(K,Q) -> lane holds S[k = kt*16 + g*4 + r][q = ln].
__global__ __launch_bounds__(256) void attn_kernel(
    const u16* __restrict__ Qp, const u16* __restrict__ Kp,
    const u16* __restrict__ Vpt, u16* __restrict__ Ctx) {
  __shared__ u16 Klds[64 * 64];
  __shared__ u16 Vlds[64 * 64];
  const int tid = threadIdx.x, w = tid >> 6, l = tid & 63, g = l >> 4, ln = l & 15;
  const int qc = blockIdx.x, bh = blockIdx.y, h = bh & 15;
  const size_t qkrow = (size_t)(bh >> 4) * SEQ;   // row base in Qp/Kp
  const size_t vrow = (size_t)bh * DKH;           // row base in Vpt
  const int q0 = qc * 64 + w * 16;

  // Q fragments (B-operand of mfma(K,Q)): lane ln -> q row, g -> d chunk
  bf8 qf[2];
#pragma unroll
  for (int c = 0; c < 2; ++c)
    qf[c] = *(const bf8*)(Qp + (qkrow + q0 + ln) * DMODEL + h * DKH + c * 32 + g * 8);

  const f4 zero = {0.f, 0.f, 0.f, 0.f};
  f4 o[4];
#pragma unroll
  for (int dt = 0; dt < 4; ++dt) o[dt] = zero;
  float m_run = -1e30f, l_run = 0.f;

  for (int t = 0; t < SEQ / 64; ++t) {
    const int kv0 = t * 64;
    __syncthreads();
#pragma unroll
    for (int p = 0; p < 2; ++p) {
      // K tile [64 k][64 d], V^T tile [64 d][64 s]; col16 pre-swizzled ^ (row&7)
      int j = p * 256 + tid;
      int row = j >> 3, cs = j & 7;
      int sc = cs ^ (row & 7);
      const u16* ga = Kp + (qkrow + kv0 + row) * DMODEL + h * DKH + sc * 8;
      GLL16(ga, &Klds[(p * 256 + w * 64) * 8]);
      const u16* gv = Vpt + (vrow + row) * SEQ + kv0 + sc * 8;
      GLL16(gv, &Vlds[(p * 256 + w * 64) * 8]);
    }
    __syncthreads();

    // S^T = K . Q^T
    f4 sf[4];
#pragma unroll
    for (int kt = 0; kt < 4; ++kt) {
      f4 s = zero;
#pragma unroll
      for (int c = 0; c < 2; ++c) {
        int row = kt * 16 + ln;
        bf8 kf = *(const bf8*)((const char*)Klds + row * 128 +
                               ((((c << 2) | g) ^ (row & 7)) << 4));
        s = MFMA16(kf, qf[c], s);
      }
      sf[kt] = s;
    }

    // online softmax for q=ln (values replicated across the 4 lane-groups)
    float mx = -1e30f;
#pragma unroll
    for (int kt = 0; kt < 4; ++kt)
#pragma unroll
      for (int r = 0; r < 4; ++r) mx = fmaxf(mx, sf[kt][r]);
    mx = fmaxf(mx, __shfl_xor(mx, 16));
    mx = fmaxf(mx, __shfl_xor(mx, 32));
    mx *= 0.125f;                       // 1/sqrt(DK)
    float m_new = fmaxf(m_run, mx);
    float alpha = __expf(m_run - m_new);
    float pv[16];
    float sum = 0.f;
#pragma unroll
    for (int kt = 0; kt < 4; ++kt)
#pragma unroll
      for (int r = 0; r < 4; ++r) {
        float p = __expf(sf[kt][r] * 0.125f - m_new);
        pv[kt * 4 + r] = p;
        sum += p;
      }
    sum += __shfl_xor(sum, 16);
    sum += __shfl_xor(sum, 32);
    l_run = l_run * alpha + sum;
    m_run = m_new;

    // pack P to bf16 pairs: pp[kt][r2] = (p_{2r2}, p_{2r2+1}) for k=kt*16+g*4+..
    unsigned pp[4][2];
#pragma unroll
    for (int kt = 0; kt < 4; ++kt)
#pragma unroll
      for (int r2 = 0; r2 < 2; ++r2)
        pp[kt][r2] = (unsigned)f2b(pv[kt * 4 + 2 * r2]) |
                     ((unsigned)f2b(pv[kt * 4 + 2 * r2 + 1]) << 16);

    // rescale O (O rows are q' = g*4+r; alpha lives at lane q')
    float ar[4];
#pragma unroll
    for (int r = 0; r < 4; ++r) ar[r] = __shfl(alpha, g * 4 + r);
#pragma unroll
    for (int dt = 0; dt < 4; ++dt)
#pragma unroll
      for (int r = 0; r < 4; ++r) o[dt][r] *= ar[r];

    // PV: A=P (lane ln -> q, needs k=c*32+8g+e), from lanes 2(g&1)(+1), kt=2c+(g>>1)
    const int sA = ln + ((g & 1) << 5);
    const int sB = sA + 16;
    const bool up = (g >= 2);
#pragma unroll
    for (int c = 0; c < 2; ++c) {
      unsigned lo0 = (unsigned)__shfl((int)pp[2 * c][0], sA);
      unsigned lo1 = (unsigned)__shfl((int)pp[2 * c][1], sA);
      unsigned lo2 = (unsigned)__shfl((int)pp[2 * c][0], sB);
      unsigned lo3 = (unsigned)__shfl((int)pp[2 * c][1], sB);
      unsigned hi0 = (unsigned)__shfl((int)pp[2 * c + 1][0], sA);
      unsigned hi1 = (unsigned)__shfl((int)pp[2 * c + 1][1], sA);
      unsigned hi2 = (unsigned)__shfl((int)pp[2 * c + 1][0], sB);
      unsigned hi3 = (unsigned)__shfl((int)pp[2 * c + 1][1], sB);
      union { u32x4 u; bf8 f; } pa;
      pa.u[0] = up ? hi0 : lo0;
      pa.u[1] = up ? hi1 : lo1;
      pa.u[2] = up ? hi2 : lo2;
      pa.u[3] = up ? hi3 : lo3;
#pragma unroll
      for (int dt = 0; dt < 4; ++dt) {
        int row = dt * 16 + ln;   // d row of V^T tile
        bf8 vf = *(const bf8*)((const char*)Vlds + row * 128 +
                               ((((c << 2) | g) ^ (row & 7)) << 4));
        o[dt] = MFMA16(pa.f, vf, o[dt]);
      }
    }
  }

  // write context: row q' = q0+g*4+r, col h*64 + dt*16 + ln
  float inv[4];
#pragma unroll
  for (int r = 0; r < 4; ++r) inv[r] = 1.0f / __shfl(l_run, g * 4 + r);
#pragma unroll
  for (int dt = 0; dt < 4; ++dt)
#pragma unroll
    for (int r = 0; r < 4; ++r)
      Ctx[(qkrow + q0 + g * 4 + r) * DMODEL + h * DKH + dt * 16 + ln] =
          f2b(o[dt][r] * inv[r]);
}

// ---------------------------------------------------------------- launch
extern "C" void kernel_launch(void* const* d_in, const int* in_sizes, int n_in,
                              void* d_out, int out_size, void* d_ws, size_t ws_size,
                              hipStream_t stream) {
  const float* Q    = (const float*)d_in[0];
  const float* K    = (const float*)d_in[1];
  const float* V    = (const float*)d_in[2];
  const float* wq_w = (const float*)d_in[3];
  const float* wq_b = (const float*)d_in[4];
  const float* wk_w = (const float*)d_in[5];
  const float* wk_b = (const float*)d_in[6];
  const float* wv_w = (const float*)d_in[7];
  const float* wv_b = (const float*)d_in[8];
  const float* ow_w = (const float*)d_in[9];
  const float* ow_b = (const float*)d_in[10];

  char* ws = (char*)d_ws;
  const size_t SZ = (size_t)MROWS * DMODEL * 2;   // 16.78 MB
  const size_t WZ = (size_t)DMODEL * DMODEL * 2;  // 2.10 MB
  u16* Qb  = (u16*)(ws);
  u16* Kb  = (u16*)(ws + SZ);
  u16* Vb  = (u16*)(ws + 2 * SZ);
  u16* Wqb = (u16*)(ws + 3 * SZ);
  u16* Wkb = (u16*)(ws + 3 * SZ + WZ);
  u16* Wvb = (u16*)(ws + 3 * SZ + 2 * WZ);
  u16* Wob = (u16*)(ws + 3 * SZ + 3 * WZ);
  u16* Qp  = (u16*)(ws + 3 * SZ + 4 * WZ);
  u16* Kp  = (u16*)(ws + 4 * SZ + 4 * WZ);
  u16* Vpt = (u16*)(ws + 5 * SZ + 4 * WZ);
  u16* Ctx = (u16*)(ws + 6 * SZ + 4 * WZ);        // total 125.8 MB

  dim3 blk(256);
  const int n8big = MROWS * DMODEL / 8;    // 1048576
  const int n8w   = DMODEL * DMODEL / 8;   // 131072
  cvt_kernel<<<2048, blk, 0, stream>>>(Q, Qb, n8big);
  cvt_kernel<<<2048, blk, 0, stream>>>(K, Kb, n8big);
  cvt_kernel<<<2048, blk, 0, stream>>>(V, Vb, n8big);
  cvt_kernel<<<512, blk, 0, stream>>>(wq_w, Wqb, n8w);
  cvt_kernel<<<512, blk, 0, stream>>>(wk_w, Wkb, n8w);
  cvt_kernel<<<512, blk, 0, stream>>>(wv_w, Wvb, n8w);
  cvt_kernel<<<512, blk, 0, stream>>>(ow_w, Wob, n8w);

  dim3 gq(DMODEL / 128, MROWS / 128, 3);
  gemm_qkv<<<gq, blk, 0, stream>>>(Qb, Kb, Vb, Wqb, Wkb, Wvb,
                                   wq_b, wk_b, wv_b, Qp, Kp, Vpt);

  dim3 ga(SEQ / 64, BATCH * NH);
  attn_kernel<<<ga, blk, 0, stream>>>(Qp, Kp, Vpt, Ctx);

  dim3 go(DMODEL / 128, MROWS / 128);
  gemm_out<<<go, blk, 0, stream>>>(Ctx, Wob, ow_b, (float*)d_out);
}